// Round 3
// baseline (322.908 us; speedup 1.0000x reference)
//
#include <hip/hip_runtime.h>
#include <hip/hip_bf16.h>
#include <stdint.h>

// Problem constants (fixed by setup_inputs)
#define NE   8
#define DOUT 2048
#define DIN  2048
#define SEQ  8192
#define GSZ  128
#define FP8_MAX 448.0f
#define EPSQ 1e-12f

typedef float f32x4  __attribute__((ext_vector_type(4)));
typedef float f32x16 __attribute__((ext_vector_type(16)));
typedef int   i32x4  __attribute__((ext_vector_type(4)));
typedef int   i32x8  __attribute__((ext_vector_type(8)));

// async global->LDS, 16B/lane. LDS dest = wave-uniform base (+lane*16 by HW);
// global src may be per-lane.
__device__ __forceinline__ void async16(void* lds_base, const void* gptr) {
    __builtin_amdgcn_global_load_lds(
        (const __attribute__((address_space(1))) unsigned int*)gptr,
        (__attribute__((address_space(3))) unsigned int*)lds_base,
        16, 0, 0);
}

// ---------------------------------------------------------------------------
// Kernel 1: per-1x128-tile quant of x. One float4 per thread; each 32-lane
// half-wave group covers one tile. Coalesced float4 loads, dword stores.
__global__ __launch_bounds__(256) void quant_x_kernel(
    const float* __restrict__ x, unsigned char* __restrict__ qx,
    float* __restrict__ sx)
{
    const int g = blockIdx.x * 256 + threadIdx.x;   // float4 group index
    const float4 v = ((const float4*)x)[g];
    float a = fmaxf(fmaxf(fabsf(v.x), fabsf(v.y)),
                    fmaxf(fabsf(v.z), fabsf(v.w)));
    #pragma unroll
    for (int o = 16; o; o >>= 1) a = fmaxf(a, __shfl_xor(a, o));  // 32-lane tile
    const float scale = fmaxf(a, EPSQ) / FP8_MAX;
    const int tile = g >> 5;                        // == row*16 + kb
    if ((threadIdx.x & 31) == 0) sx[tile] = scale;

    float q0 = fminf(fmaxf(v.x / scale, -FP8_MAX), FP8_MAX);
    float q1 = fminf(fmaxf(v.y / scale, -FP8_MAX), FP8_MAX);
    float q2 = fminf(fmaxf(v.z / scale, -FP8_MAX), FP8_MAX);
    float q3 = fminf(fmaxf(v.w / scale, -FP8_MAX), FP8_MAX);
    int lo = __builtin_amdgcn_cvt_pk_fp8_f32(q0, q1, 0, false);
    int pk = __builtin_amdgcn_cvt_pk_fp8_f32(q2, q3, lo, true);
    ((unsigned int*)qx)[g] = (unsigned int)pk;
}

// ---------------------------------------------------------------------------
// Kernel 2: per-128x128-block quant of w. Stage block into 64 KB LDS via
// global_load_lds, amax from LDS, quantize from LDS.
__global__ __launch_bounds__(256) void quant_w_kernel(
    const float* __restrict__ w, unsigned char* __restrict__ qw,
    float* __restrict__ sw)
{
    __shared__ float buf[128 * 128];   // 64 KB
    __shared__ float red[4];

    const int cb = blockIdx.x;   // din block 0..15
    const int rb = blockIdx.y;   // dout block 0..15
    const int e  = blockIdx.z;   // expert 0..7
    const int t  = threadIdx.x;
    const int lane = t & 63, wv = t >> 6;

    const size_t base = ((size_t)e * DOUT + rb * GSZ) * DIN + cb * GSZ;
    const float* wp = w + base;

    // stage 64 KB: 4 waves x 16 iters x 1 KB. 32 sixteen-byte chunks per row.
    #pragma unroll
    for (int j = 0; j < 16; ++j) {
        int f16 = (wv * 16 + j) * 64 + lane;     // 16-byte chunk index 0..4095
        int row = f16 >> 5, cc = f16 & 31;
        async16(buf + (wv * 16 + j) * 256,
                wp + (size_t)row * DIN + cc * 4);
    }
    __syncthreads();

    float a = 0.f;
    #pragma unroll
    for (int i = 0; i < 16; ++i) {
        f32x4 v = *(const f32x4*)(buf + (t + i * 256) * 4);
        a = fmaxf(a, fmaxf(fmaxf(fabsf(v[0]), fabsf(v[1])),
                           fmaxf(fabsf(v[2]), fabsf(v[3]))));
    }
    #pragma unroll
    for (int o = 32; o; o >>= 1) a = fmaxf(a, __shfl_xor(a, o));
    if (lane == 0) red[wv] = a;
    __syncthreads();
    a = fmaxf(fmaxf(red[0], red[1]), fmaxf(red[2], red[3]));
    const float scale = fmaxf(a, EPSQ) / FP8_MAX;
    if (t == 0) sw[(e * 16 + rb) * 16 + cb] = scale;

    unsigned int* qout = (unsigned int*)(qw + base);
    #pragma unroll
    for (int i = 0; i < 16; ++i) {
        int idx = t + i * 256;
        f32x4 v = *(const f32x4*)(buf + idx * 4);
        float q0 = fminf(fmaxf(v[0] / scale, -FP8_MAX), FP8_MAX);
        float q1 = fminf(fmaxf(v[1] / scale, -FP8_MAX), FP8_MAX);
        float q2 = fminf(fmaxf(v[2] / scale, -FP8_MAX), FP8_MAX);
        float q3 = fminf(fmaxf(v[3] / scale, -FP8_MAX), FP8_MAX);
        int lo = __builtin_amdgcn_cvt_pk_fp8_f32(q0, q1, 0, false);
        int pk = __builtin_amdgcn_cvt_pk_fp8_f32(q2, q3, lo, true);
        int r = idx >> 5, c4 = idx & 31;
        qout[r * (DIN / 4) + c4] = (unsigned int)pk;
    }
}

// ---------------------------------------------------------------------------
// Kernel 3: grouped fp8 GEMM, 256x256 tile, 4-phase counted-vmcnt schedule
// (T3+T4), MX-scaled MFMA 32x32x64 fp8 with unit e8m0 scales, T2 XOR-swizzled
// LDS, T5 setprio, XCD-contiguous block decomposition (T1).
//
// Telescoped per-128-k-block rescale, split row x col:
//   c[s,j] = sx[s,j] * sw[e, n128, j]
//   A_j = A_{j-1} * (Rs[j][s] * SwL[nh][j]) + P_j ;  out = A_15 * Rs[0][s]*SwL[nh][0]
//   Rs[j][s]  = sx[s,j-1]/sx[s,j]  (j>0),  Rs[0][s]  = sx[s,15]
//   SwL[nh][j]= sw[j-1]/sw[j]      (j>0),  SwL[nh][0]= sw[15]     (nh = col half)
//
// 8 waves (2M x 4N): wave = 128x64 out = acc[4][2] f32x16 (128 VGPR).
// K-step kb: 4 phases; phase p = {ds_read A[mi=p] (+all B if p==0) ||
//   issue 2 global_load_lds into next buffer -> barrier -> rescale+4 MFMA ->
//   barrier}. vmcnt(2) counted wait once per K-step (phase 0); never 0 in loop.
// LDS: 2x(A 32K)+2x(B 32K) dbuf + Rs 16K + SwL = ~144 KB -> 1 block/CU.
__global__ __launch_bounds__(512, 2) void gemm_kernel(
    const unsigned char* __restrict__ qx, const float* __restrict__ sx,
    const unsigned char* __restrict__ qw, const float* __restrict__ sw,
    const int* __restrict__ tpe, float* __restrict__ out)
{
    __shared__ __align__(16) unsigned char Asm[2][256 * 128];
    __shared__ __align__(16) unsigned char Bsm[2][256 * 128];
    __shared__ __align__(16) float Rs[16 * 256];   // [kb][row], sx-part
    __shared__ __align__(16) float SwL[2 * 16];    // [nh][kb], sw-part

    const int tid  = threadIdx.x;
    const int lane = tid & 63;
    const int wv   = tid >> 6;          // 0..7
    const int wm   = wv >> 2;           // 0..1  (M half)
    const int wn   = wv & 3;            // 0..3  (N quarter)
    const int l31  = lane & 31;
    const int h    = lane >> 5;
    const int nh   = wn >> 1;           // which 128-col half of the 256 N-tile

    // XCD-contiguous decomposition: XCD c gets mb in [4c, 4c+4), all nb.
    const int lid  = blockIdx.x;        // 0..255
    const int xcd  = lid & 7, t8 = lid >> 3;
    const int mbid = xcd * 4 + (t8 >> 3);   // 0..31
    const int nb   = t8 & 7;                // 0..7
    const int r0   = mbid * 256, n0 = nb * 256;

    int e = -1, start = 0;
    #pragma unroll
    for (int i = 0; i < NE; ++i) {
        int end = start + tpe[i];
        if (r0 >= start && r0 < end) e = i;
        start = end;
    }
    if (e < 0) {
        f32x4 z = {0.f, 0.f, 0.f, 0.f};
        for (int i = tid; i < 256 * 64; i += 512) {
            int r = i >> 6, c4 = i & 63;
            *(f32x4*)(out + (size_t)(r0 + r) * DOUT + n0 + c4 * 4) = z;
        }
        return;
    }

    // ---- prologue: scale ratio tables ----
    for (int i = tid; i < 16 * 256; i += 512) {
        int row = i >> 4, kb = i & 15;
        const float* sp = sx + (size_t)(r0 + row) * 16;
        Rs[kb * 256 + row] = (kb == 0) ? sp[15] : sp[kb - 1] / sp[kb];
    }
    if (tid < 32) {
        int nhh = tid >> 4, kb = tid & 15;
        const float* wp = sw + ((e * 16) + (nb * 2 + nhh)) * 16;
        SwL[nhh * 16 + kb] = (kb == 0) ? wp[15] : wp[kb - 1] / wp[kb];
    }

    const unsigned char* Ag = qx + (size_t)r0 * DIN;
    const unsigned char* Bg = qw + (size_t)e * DOUT * DIN + (size_t)n0 * DIN;

    // staging: wave stages 4 KB of A + 4 KB of B per K-step (1 KB each/phase).
    // 16B-chunk XOR swizzle within each 128 B row: pos = chunk ^ (row&7).
    int soff[4], ldst[4];
    #pragma unroll
    for (int j = 0; j < 4; ++j) {
        int f = wv * 4096 + j * 1024 + lane * 16;   // byte index in 32 KB tile
        int row = f >> 7, pc = (f >> 4) & 7;
        soff[j] = row * DIN + ((pc ^ (row & 7)) * 16);  // + kb*128 at use
        ldst[j] = wv * 4096 + j * 1024;
    }

    // fragment read bases (A row = wm*128+mi*32+l31, B row = wn*64+ni*32+l31)
    int abase[4], ax8[4], bbase[2], bx8[2];
    #pragma unroll
    for (int mi = 0; mi < 4; ++mi) {
        int ra = wm * 128 + mi * 32 + l31;
        abase[mi] = ra * 128; ax8[mi] = ra & 7;
    }
    #pragma unroll
    for (int ni = 0; ni < 2; ++ni) {
        int rb = wn * 64 + ni * 32 + l31;
        bbase[ni] = rb * 128; bx8[ni] = rb & 7;
    }

    // stage kb=0 into buffer 0
    #pragma unroll
    for (int j = 0; j < 4; ++j) {
        async16(Asm[0] + ldst[j], Ag + soff[j]);
        async16(Bsm[0] + ldst[j], Bg + soff[j]);
    }
    // Rs/SwL writes drained before any wave can pass the first in-loop barrier
    asm volatile("s_waitcnt lgkmcnt(0)" ::: "memory");

    f32x16 acc[4][2];
    #pragma unroll
    for (int mi = 0; mi < 4; ++mi)
        #pragma unroll
        for (int ni = 0; ni < 2; ++ni)
            #pragma unroll
            for (int q = 0; q < 16; ++q) acc[mi][ni][q] = 0.f;

    for (int kb = 0; kb < 16; ++kb) {
        const unsigned char* Ac = Asm[kb & 1];
        const unsigned char* Bc = Bsm[kb & 1];
        unsigned char* An = Asm[(kb & 1) ^ 1];
        unsigned char* Bn = Bsm[(kb & 1) ^ 1];
        float rwk = 1.f;
        i32x8 Bf[2][2];   // [ks][ni], held across phases

        #pragma unroll
        for (int p = 0; p < 4; ++p) {
            // issue next-tile staging (2 loads/phase; 8/K-step/wave)
            if (kb < 15) {
                async16(An + ldst[p], Ag + soff[p] + (kb + 1) * GSZ);
                async16(Bn + ldst[p], Bg + soff[p] + (kb + 1) * GSZ);
            }
            if (p == 0) {
                // counted wait: the 8 current-tile loads (issued last K-step)
                // are older than the 2 just issued -> vmcnt(2) completes them.
                if (kb < 15) asm volatile("s_waitcnt vmcnt(2)" ::: "memory");
                else         asm volatile("s_waitcnt vmcnt(0)" ::: "memory");
                __builtin_amdgcn_s_barrier();
                asm volatile("" ::: "memory");
            }
            // ds_reads for this phase (data valid since phase-0 wait+barrier)
            if (p == 0) {
                #pragma unroll
                for (int ks = 0; ks < 2; ++ks) {
                    const int c0 = ks * 4 + h * 2;
                    #pragma unroll
                    for (int ni = 0; ni < 2; ++ni) {
                        i32x4 lo = *(const i32x4*)(Bc + bbase[ni] + (((c0    ) ^ bx8[ni]) * 16));
                        i32x4 hi = *(const i32x4*)(Bc + bbase[ni] + (((c0 + 1) ^ bx8[ni]) * 16));
                        #pragma unroll
                        for (int q = 0; q < 4; ++q) {
                            Bf[ks][ni][q] = lo[q]; Bf[ks][ni][q + 4] = hi[q];
                        }
                    }
                }
                rwk = SwL[nh * 16 + kb];
            }
            i32x8 Af[2];
            #pragma unroll
            for (int ks = 0; ks < 2; ++ks) {
                const int c0 = ks * 4 + h * 2;
                i32x4 lo = *(const i32x4*)(Ac + abase[p] + (((c0    ) ^ ax8[p]) * 16));
                i32x4 hi = *(const i32x4*)(Ac + abase[p] + (((c0 + 1) ^ ax8[p]) * 16));
                #pragma unroll
                for (int q = 0; q < 4; ++q) { Af[ks][q] = lo[q]; Af[ks][q + 4] = hi[q]; }
            }
            f32x4 rr[4];
            if (kb) {
                const float* rp = Rs + kb * 256 + wm * 128 + p * 32 + 4 * h;
                #pragma unroll
                for (int g = 0; g < 4; ++g) {
                    f32x4 t = *(const f32x4*)(rp + 8 * g);
                    rr[g] = t * rwk;
                }
            }

            __builtin_amdgcn_s_barrier();
            __builtin_amdgcn_s_setprio(1);
            if (kb) {   // rescale acc[p] into this k-block's units
                #pragma unroll
                for (int ni = 0; ni < 2; ++ni)
                    #pragma unroll
                    for (int g = 0; g < 4; ++g)
                        #pragma unroll
                        for (int j = 0; j < 4; ++j)
                            acc[p][ni][g * 4 + j] *= rr[g][j];
            }
            #pragma unroll
            for (int ks = 0; ks < 2; ++ks)
                #pragma unroll
                for (int ni = 0; ni < 2; ++ni)
                    acc[p][ni] = __builtin_amdgcn_mfma_scale_f32_32x32x64_f8f6f4(
                        Af[ks], Bf[ks][ni], acc[p][ni],
                        0, 0,                       // cbsz=fp8, blgp=fp8
                        0, 0x7f7f7f7f,              // A scale: e8m0 1.0
                        0, 0x7f7f7f7f);             // B scale: e8m0 1.0
            __builtin_amdgcn_s_setprio(0);
            __builtin_amdgcn_s_barrier();
        }
    }

    // epilogue: final scale = Rs[0][row] * SwL[nh][0].
    // C/D: col = l31, row = (reg&3) + 8*(reg>>2) + 4*h
    const float fw = SwL[nh * 16 + 0];
    #pragma unroll
    for (int mi = 0; mi < 4; ++mi) {
        const float* fp = Rs + wm * 128 + mi * 32 + 4 * h;
        f32x4 fv[4];
        #pragma unroll
        for (int g = 0; g < 4; ++g) {
            f32x4 t = *(const f32x4*)(fp + 8 * g);
            fv[g] = t * fw;
        }
        const int rbase = r0 + wm * 128 + mi * 32 + 4 * h;
        #pragma unroll
        for (int ni = 0; ni < 2; ++ni) {
            const int col = n0 + wn * 64 + ni * 32 + l31;
            #pragma unroll
            for (int g = 0; g < 4; ++g)
                #pragma unroll
                for (int j = 0; j < 4; ++j)
                    out[(size_t)(rbase + 8 * g + j) * DOUT + col] =
                        acc[mi][ni][g * 4 + j] * fv[g][j];
        }
    }
}

// ---------------------------------------------------------------------------
extern "C" void kernel_launch(void* const* d_in, const int* in_sizes, int n_in,
                              void* d_out, int out_size, void* d_ws, size_t ws_size,
                              hipStream_t stream) {
    const float* x   = (const float*)d_in[0];   // [8192, 2048] fp32
    const float* wt  = (const float*)d_in[1];   // [16384, 2048] fp32
    const int*   tpe = (const int*)d_in[2];     // [8]
    float* out = (float*)d_out;                 // [8192, 2048] fp32

    char* ws = (char*)d_ws;
    unsigned char* qx = (unsigned char*)ws;                       // 16 MB
    unsigned char* qw = qx + (size_t)SEQ * DIN;                   // 32 MB
    float* sx = (float*)(qw + (size_t)NE * DOUT * DIN);           // 512 KB
    float* sw = sx + (size_t)SEQ * 16;                            // 4 KB

    quant_x_kernel<<<SEQ * DIN / 4 / 256, 256, 0, stream>>>(x, qx, sx);
    quant_w_kernel<<<dim3(16, 16, NE), 256, 0, stream>>>(wt, qw, sw);
    gemm_kernel<<<256, 512, 0, stream>>>(qx, sx, qw, sw, tpe, out);
}

// Round 4
// 302.389 us; speedup vs baseline: 1.0679x; 1.0679x over previous
//
#include <hip/hip_runtime.h>
#include <hip/hip_bf16.h>
#include <stdint.h>

// Problem constants (fixed by setup_inputs)
#define NE   8
#define DOUT 2048
#define DIN  2048
#define SEQ  8192
#define GSZ  128
#define FP8_MAX 448.0f
#define EPSQ 1e-12f

typedef float f32x4  __attribute__((ext_vector_type(4)));
typedef float f32x16 __attribute__((ext_vector_type(16)));
typedef int   i32x4  __attribute__((ext_vector_type(4)));
typedef int   i32x8  __attribute__((ext_vector_type(8)));

// async global->LDS, 16B/lane. LDS dest = wave-uniform base (+lane*16 by HW);
// global src may be per-lane.
__device__ __forceinline__ void async16(void* lds_base, const void* gptr) {
    __builtin_amdgcn_global_load_lds(
        (const __attribute__((address_space(1))) unsigned int*)gptr,
        (__attribute__((address_space(3))) unsigned int*)lds_base,
        16, 0, 0);
}

// ---------------------------------------------------------------------------
// Kernel 1: per-1x128-tile quant of x. One float4 per thread; each 32-lane
// half-wave group covers one tile. Coalesced float4 loads, dword stores.
__global__ __launch_bounds__(256) void quant_x_kernel(
    const float* __restrict__ x, unsigned char* __restrict__ qx,
    float* __restrict__ sx)
{
    const int g = blockIdx.x * 256 + threadIdx.x;   // float4 group index
    const float4 v = ((const float4*)x)[g];
    float a = fmaxf(fmaxf(fabsf(v.x), fabsf(v.y)),
                    fmaxf(fabsf(v.z), fabsf(v.w)));
    #pragma unroll
    for (int o = 16; o; o >>= 1) a = fmaxf(a, __shfl_xor(a, o));  // 32-lane tile
    const float scale = fmaxf(a, EPSQ) / FP8_MAX;
    const int tile = g >> 5;                        // == row*16 + kb
    if ((threadIdx.x & 31) == 0) sx[tile] = scale;

    float q0 = fminf(fmaxf(v.x / scale, -FP8_MAX), FP8_MAX);
    float q1 = fminf(fmaxf(v.y / scale, -FP8_MAX), FP8_MAX);
    float q2 = fminf(fmaxf(v.z / scale, -FP8_MAX), FP8_MAX);
    float q3 = fminf(fmaxf(v.w / scale, -FP8_MAX), FP8_MAX);
    int lo = __builtin_amdgcn_cvt_pk_fp8_f32(q0, q1, 0, false);
    int pk = __builtin_amdgcn_cvt_pk_fp8_f32(q2, q3, lo, true);
    ((unsigned int*)qx)[g] = (unsigned int)pk;
}

// ---------------------------------------------------------------------------
// Kernel 2: per-128x128-block quant of w. Stage block into 64 KB LDS via
// global_load_lds, amax from LDS, quantize from LDS.
__global__ __launch_bounds__(256) void quant_w_kernel(
    const float* __restrict__ w, unsigned char* __restrict__ qw,
    float* __restrict__ sw)
{
    __shared__ float buf[128 * 128];   // 64 KB
    __shared__ float red[4];

    const int cb = blockIdx.x;   // din block 0..15
    const int rb = blockIdx.y;   // dout block 0..15
    const int e  = blockIdx.z;   // expert 0..7
    const int t  = threadIdx.x;
    const int lane = t & 63, wv = t >> 6;

    const size_t base = ((size_t)e * DOUT + rb * GSZ) * DIN + cb * GSZ;
    const float* wp = w + base;

    // stage 64 KB: 4 waves x 16 iters x 1 KB. 32 sixteen-byte chunks per row.
    #pragma unroll
    for (int j = 0; j < 16; ++j) {
        int f16 = (wv * 16 + j) * 64 + lane;     // 16-byte chunk index 0..4095
        int row = f16 >> 5, cc = f16 & 31;
        async16(buf + (wv * 16 + j) * 256,
                wp + (size_t)row * DIN + cc * 4);
    }
    __syncthreads();

    float a = 0.f;
    #pragma unroll
    for (int i = 0; i < 16; ++i) {
        f32x4 v = *(const f32x4*)(buf + (t + i * 256) * 4);
        a = fmaxf(a, fmaxf(fmaxf(fabsf(v[0]), fabsf(v[1])),
                           fmaxf(fabsf(v[2]), fabsf(v[3]))));
    }
    #pragma unroll
    for (int o = 32; o; o >>= 1) a = fmaxf(a, __shfl_xor(a, o));
    if (lane == 0) red[wv] = a;
    __syncthreads();
    a = fmaxf(fmaxf(red[0], red[1]), fmaxf(red[2], red[3]));
    const float scale = fmaxf(a, EPSQ) / FP8_MAX;
    if (t == 0) sw[(e * 16 + rb) * 16 + cb] = scale;

    unsigned int* qout = (unsigned int*)(qw + base);
    #pragma unroll
    for (int i = 0; i < 16; ++i) {
        int idx = t + i * 256;
        f32x4 v = *(const f32x4*)(buf + idx * 4);
        float q0 = fminf(fmaxf(v[0] / scale, -FP8_MAX), FP8_MAX);
        float q1 = fminf(fmaxf(v[1] / scale, -FP8_MAX), FP8_MAX);
        float q2 = fminf(fmaxf(v[2] / scale, -FP8_MAX), FP8_MAX);
        float q3 = fminf(fmaxf(v[3] / scale, -FP8_MAX), FP8_MAX);
        int lo = __builtin_amdgcn_cvt_pk_fp8_f32(q0, q1, 0, false);
        int pk = __builtin_amdgcn_cvt_pk_fp8_f32(q2, q3, lo, true);
        int r = idx >> 5, c4 = idx & 31;
        qout[r * (DIN / 4) + c4] = (unsigned int)pk;
    }
}

// ---------------------------------------------------------------------------
// Kernel 3: grouped fp8 GEMM, 256x256 tile, double-buffered LDS with
// counted-vmcnt 2-barrier K-loop (T3-minimum), MX-scaled MFMA 32x32x64 fp8
// (unit e8m0 scales), XCD-contiguous block decomposition.
//
// Per K-step kb: {issue 8 global_load_lds -> next buffer; s_waitcnt vmcnt(8)
// (waits only kb-1's loads; this kb's stay in flight); barrier;
// rescale acc || 24 x ds_read_b128 || 16 MFMA (setprio); barrier}.
// No vmcnt(0) drain inside the loop.
//
// Telescoped per-128-k-block rescale, split row x col:
//   c[s,j] = sx[s,j] * sw[e, n128, j]
//   A_j = A_{j-1} * (Rs[j][s] * SwL[nh][j]) + P_j ;  out = A_15 * Rs[0][s]*SwL[nh][0]
// 8 waves (2M x 4N): wave = 128x64 out = acc[4][2] f32x16 (128 regs).
// LDS: 2x(A 32K + B 32K) dbuf + Rs 16K + SwL = ~144 KB -> 1 block/CU, 8 waves.
__global__ __launch_bounds__(512, 2) void gemm_kernel(
    const unsigned char* __restrict__ qx, const float* __restrict__ sx,
    const unsigned char* __restrict__ qw, const float* __restrict__ sw,
    const int* __restrict__ tpe, float* __restrict__ out)
{
    __shared__ __align__(16) unsigned char Asm[2][256 * 128];
    __shared__ __align__(16) unsigned char Bsm[2][256 * 128];
    __shared__ __align__(16) float Rs[16 * 256];   // [kb][row], sx-part
    __shared__ __align__(16) float SwL[2 * 16];    // [nh][kb], sw-part

    const int tid  = threadIdx.x;
    const int lane = tid & 63;
    const int wv   = tid >> 6;          // 0..7
    const int wm   = wv >> 2;           // 0..1  (M half)
    const int wn   = wv & 3;            // 0..3  (N quarter)
    const int l31  = lane & 31;
    const int h    = lane >> 5;
    const int nh   = wn >> 1;           // which 128-col half of the 256 N-tile

    // XCD-contiguous decomposition: XCD c gets mb in [4c, 4c+4), all nb.
    const int lid  = blockIdx.x;        // 0..255
    const int xcd  = lid & 7, t8 = lid >> 3;
    const int mbid = xcd * 4 + (t8 >> 3);   // 0..31
    const int nb   = t8 & 7;                // 0..7
    const int r0   = mbid * 256, n0 = nb * 256;

    int e = -1, start = 0;
    #pragma unroll
    for (int i = 0; i < NE; ++i) {
        int end = start + tpe[i];
        if (r0 >= start && r0 < end) e = i;
        start = end;
    }
    if (e < 0) {
        f32x4 z = {0.f, 0.f, 0.f, 0.f};
        for (int i = tid; i < 256 * 64; i += 512) {
            int r = i >> 6, c4 = i & 63;
            *(f32x4*)(out + (size_t)(r0 + r) * DOUT + n0 + c4 * 4) = z;
        }
        return;
    }

    // ---- prologue: scale ratio tables ----
    for (int i = tid; i < 16 * 256; i += 512) {
        int row = i >> 4, kb = i & 15;
        const float* sp = sx + (size_t)(r0 + row) * 16;
        Rs[kb * 256 + row] = (kb == 0) ? sp[15] : sp[kb - 1] / sp[kb];
    }
    if (tid < 32) {
        int nhh = tid >> 4, kb = tid & 15;
        const float* wp = sw + ((e * 16) + (nb * 2 + nhh)) * 16;
        SwL[nhh * 16 + kb] = (kb == 0) ? wp[15] : wp[kb - 1] / wp[kb];
    }

    const unsigned char* Ag = qx + (size_t)r0 * DIN;
    const unsigned char* Bg = qw + (size_t)e * DOUT * DIN + (size_t)n0 * DIN;

    // staging: wave stages 4 KB of A + 4 KB of B per K-step.
    // 16B-chunk XOR swizzle within each 128 B row: pos = chunk ^ (row&7).
    int soff[4], ldst[4];
    #pragma unroll
    for (int j = 0; j < 4; ++j) {
        int f = wv * 4096 + j * 1024 + lane * 16;   // byte index in 32 KB tile
        int row = f >> 7, pc = (f >> 4) & 7;
        soff[j] = row * DIN + ((pc ^ (row & 7)) * 16);  // + kb*128 at use
        ldst[j] = wv * 4096 + j * 1024;
    }

    // fragment read bases (A row = wm*128+mi*32+l31, B row = wn*64+ni*32+l31)
    int abase[4], ax8[4], bbase[2], bx8[2];
    #pragma unroll
    for (int mi = 0; mi < 4; ++mi) {
        int ra = wm * 128 + mi * 32 + l31;
        abase[mi] = ra * 128; ax8[mi] = ra & 7;
    }
    #pragma unroll
    for (int ni = 0; ni < 2; ++ni) {
        int rb = wn * 64 + ni * 32 + l31;
        bbase[ni] = rb * 128; bx8[ni] = rb & 7;
    }

    // stage kb=0 into buffer 0
    #pragma unroll
    for (int j = 0; j < 4; ++j) {
        async16(Asm[0] + ldst[j], Ag + soff[j]);
        async16(Bsm[0] + ldst[j], Bg + soff[j]);
    }
    // own Rs/SwL ds_writes drained before first barrier (all waves do this)
    asm volatile("s_waitcnt lgkmcnt(0)" ::: "memory");

    f32x16 acc[4][2];
    #pragma unroll
    for (int mi = 0; mi < 4; ++mi)
        #pragma unroll
        for (int ni = 0; ni < 2; ++ni)
            #pragma unroll
            for (int q = 0; q < 16; ++q) acc[mi][ni][q] = 0.f;

    for (int kb = 0; kb < 16; ++kb) {
        const unsigned char* Ac = Asm[kb & 1];
        const unsigned char* Bc = Bsm[kb & 1];

        if (kb < 15) {
            unsigned char* An = Asm[(kb & 1) ^ 1];
            unsigned char* Bn = Bsm[(kb & 1) ^ 1];
            #pragma unroll
            for (int j = 0; j < 4; ++j) {
                async16(An + ldst[j], Ag + soff[j] + (kb + 1) * GSZ);
                async16(Bn + ldst[j], Bg + soff[j] + (kb + 1) * GSZ);
            }
            // wait only the 8 older loads (current buffer); keep 8 in flight
            asm volatile("s_waitcnt vmcnt(8)" ::: "memory");
        } else {
            asm volatile("s_waitcnt vmcnt(0)" ::: "memory");
        }
        __builtin_amdgcn_s_barrier();
        asm volatile("" ::: "memory");

        if (kb) {   // rescale accumulators into this k-block's units
            const float rwk = SwL[nh * 16 + kb];
            #pragma unroll
            for (int mi = 0; mi < 4; ++mi) {
                const float* rp = Rs + kb * 256 + wm * 128 + mi * 32 + 4 * h;
                f32x4 rr[4];
                #pragma unroll
                for (int g = 0; g < 4; ++g) {
                    f32x4 t = *(const f32x4*)(rp + 8 * g);
                    rr[g] = t * rwk;
                }
                #pragma unroll
                for (int ni = 0; ni < 2; ++ni)
                    #pragma unroll
                    for (int g = 0; g < 4; ++g)
                        #pragma unroll
                        for (int j = 0; j < 4; ++j)
                            acc[mi][ni][g * 4 + j] *= rr[g][j];
            }
        }

        __builtin_amdgcn_s_setprio(1);
        #pragma unroll
        for (int ks = 0; ks < 2; ++ks) {
            const int c0 = ks * 4 + h * 2;
            i32x8 Bf[2];
            #pragma unroll
            for (int ni = 0; ni < 2; ++ni) {
                i32x4 lo = *(const i32x4*)(Bc + bbase[ni] + (((c0    ) ^ bx8[ni]) * 16));
                i32x4 hi = *(const i32x4*)(Bc + bbase[ni] + (((c0 + 1) ^ bx8[ni]) * 16));
                #pragma unroll
                for (int q = 0; q < 4; ++q) { Bf[ni][q] = lo[q]; Bf[ni][q + 4] = hi[q]; }
            }
            #pragma unroll
            for (int mi = 0; mi < 4; ++mi) {
                i32x8 Af;
                i32x4 alo = *(const i32x4*)(Ac + abase[mi] + (((c0    ) ^ ax8[mi]) * 16));
                i32x4 ahi = *(const i32x4*)(Ac + abase[mi] + (((c0 + 1) ^ ax8[mi]) * 16));
                #pragma unroll
                for (int q = 0; q < 4; ++q) { Af[q] = alo[q]; Af[q + 4] = ahi[q]; }
                #pragma unroll
                for (int ni = 0; ni < 2; ++ni)
                    acc[mi][ni] = __builtin_amdgcn_mfma_scale_f32_32x32x64_f8f6f4(
                        Af, Bf[ni], acc[mi][ni],
                        0, 0,                       // cbsz=fp8, blgp=fp8
                        0, 0x7f7f7f7f,              // A scale: e8m0 1.0
                        0, 0x7f7f7f7f);             // B scale: e8m0 1.0
            }
        }
        __builtin_amdgcn_s_setprio(0);
        asm volatile("" ::: "memory");
        __builtin_amdgcn_s_barrier();
        asm volatile("" ::: "memory");
    }

    // epilogue: final scale = Rs[0][row] * SwL[nh][0].
    // C/D: col = l31, row = (reg&3) + 8*(reg>>2) + 4*h
    const float fw = SwL[nh * 16 + 0];
    #pragma unroll
    for (int mi = 0; mi < 4; ++mi) {
        const float* fp = Rs + wm * 128 + mi * 32 + 4 * h;
        f32x4 fv[4];
        #pragma unroll
        for (int g = 0; g < 4; ++g) {
            f32x4 t = *(const f32x4*)(fp + 8 * g);
            fv[g] = t * fw;
        }
        const int rbase = r0 + wm * 128 + mi * 32 + 4 * h;
        #pragma unroll
        for (int ni = 0; ni < 2; ++ni) {
            const int col = n0 + wn * 64 + ni * 32 + l31;
            #pragma unroll
            for (int g = 0; g < 4; ++g)
                #pragma unroll
                for (int j = 0; j < 4; ++j)
                    out[(size_t)(rbase + 8 * g + j) * DOUT + col] =
                        acc[mi][ni][g * 4 + j] * fv[g][j];
        }
    }
}

// ---------------------------------------------------------------------------
extern "C" void kernel_launch(void* const* d_in, const int* in_sizes, int n_in,
                              void* d_out, int out_size, void* d_ws, size_t ws_size,
                              hipStream_t stream) {
    const float* x   = (const float*)d_in[0];   // [8192, 2048] fp32
    const float* wt  = (const float*)d_in[1];   // [16384, 2048] fp32
    const int*   tpe = (const int*)d_in[2];     // [8]
    float* out = (float*)d_out;                 // [8192, 2048] fp32

    char* ws = (char*)d_ws;
    unsigned char* qx = (unsigned char*)ws;                       // 16 MB
    unsigned char* qw = qx + (size_t)SEQ * DIN;                   // 32 MB
    float* sx = (float*)(qw + (size_t)NE * DOUT * DIN);           // 512 KB
    float* sw = sx + (size_t)SEQ * 16;                            // 4 KB

    quant_x_kernel<<<SEQ * DIN / 4 / 256, 256, 0, stream>>>(x, qx, sx);
    quant_w_kernel<<<dim3(16, 16, NE), 256, 0, stream>>>(wt, qw, sw);
    gemm_kernel<<<256, 512, 0, stream>>>(qx, sx, qw, sw, tpe, out);
}